// Round 1
// baseline (20.556 us; speedup 1.0000x reference)
//
#include <hip/hip_runtime.h>
#include <hip/hip_bf16.h>

// EdgePrompt: out[e] = edge_weight[e] * sigmoid( x[src[e]]·W[:d] + x[dst[e]]·W[d:] + b )
// Strategy: pre-project nodes once (proj_src[n], proj_dst[n]) then do a cheap
// per-edge gather. proj tables (2 x 50000 x f32 = 400 KB) live in d_ws and
// are fully L2-resident for the gather.

#define IN_DIM 128

// One 64-lane wave per node: lane i owns x[n][2i], x[n][2i+1] (float2, 8B/lane,
// coalesced). Butterfly-reduce both dots simultaneously.
__global__ void __launch_bounds__(256)
edgeprompt_proj_kernel(const float* __restrict__ x,
                       const float* __restrict__ W,
                       float* __restrict__ proj,   // [2 * n_nodes]: [0..N)=src, [N..2N)=dst
                       int n_nodes) {
    const int lane = threadIdx.x & 63;
    const int wave = (blockIdx.x * blockDim.x + threadIdx.x) >> 6;
    const int nwaves = (gridDim.x * blockDim.x) >> 6;

    // W is tiny (1 KB) and node-invariant: hoist the per-lane pair loads.
    const float2 w0 = *reinterpret_cast<const float2*>(&W[lane * 2]);
    const float2 w1 = *reinterpret_cast<const float2*>(&W[IN_DIM + lane * 2]);

    for (int n = wave; n < n_nodes; n += nwaves) {
        const float2 xv = *reinterpret_cast<const float2*>(&x[(size_t)n * IN_DIM + lane * 2]);
        float ps = xv.x * w0.x + xv.y * w0.y;
        float pd = xv.x * w1.x + xv.y * w1.y;
        // 64-lane butterfly reduction
        #pragma unroll
        for (int off = 32; off > 0; off >>= 1) {
            ps += __shfl_xor(ps, off);
            pd += __shfl_xor(pd, off);
        }
        if (lane == 0) {
            proj[n] = ps;
            proj[n_nodes + n] = pd;
        }
    }
}

__global__ void __launch_bounds__(256)
edgeprompt_edge_kernel(const int* __restrict__ edge_index,   // [2 * n_edges], row0=src, row1=dst
                       const float* __restrict__ edge_weight,
                       const float* __restrict__ proj,       // [2 * n_nodes]
                       const float* __restrict__ bias_p,
                       float* __restrict__ out,
                       int n_edges, int n_nodes) {
    const int tid = blockIdx.x * blockDim.x + threadIdx.x;
    const int stride = gridDim.x * blockDim.x;
    const float bias = bias_p[0];
    for (int e = tid; e < n_edges; e += stride) {
        const int s = edge_index[e];
        const int d = edge_index[n_edges + e];
        const float logit = proj[s] + proj[n_nodes + d] + bias;
        const float sig = 1.0f / (1.0f + __expf(-logit));
        out[e] = edge_weight[e] * sig;
    }
}

extern "C" void kernel_launch(void* const* d_in, const int* in_sizes, int n_in,
                              void* d_out, int out_size, void* d_ws, size_t ws_size,
                              hipStream_t stream) {
    // setup_inputs() order: x, edge_index, edge_weight, W, b
    const float* x           = (const float*)d_in[0];
    const int*   edge_index  = (const int*)d_in[1];
    const float* edge_weight = (const float*)d_in[2];
    const float* W           = (const float*)d_in[3];
    const float* b           = (const float*)d_in[4];
    float* out = (float*)d_out;

    const int n_nodes = in_sizes[0] / IN_DIM;       // 50000
    const int n_edges = in_sizes[2];                // 500000 (edge_weight is [E])

    float* proj = (float*)d_ws;                     // 2 * n_nodes floats = 400 KB

    // Kernel 1: one wave per node; 256 threads = 4 nodes/block.
    const int blocks1 = (n_nodes + 3) / 4;
    edgeprompt_proj_kernel<<<blocks1, 256, 0, stream>>>(x, W, proj, n_nodes);

    // Kernel 2: one thread per edge.
    const int blocks2 = (n_edges + 255) / 256;
    edgeprompt_edge_kernel<<<blocks2, 256, 0, stream>>>(edge_index, edge_weight, proj, b,
                                                        out, n_edges, n_nodes);
}